// Round 1
// 2362.856 us; speedup vs baseline: 1.2155x; 1.2155x over previous
//
#include <hip/hip_runtime.h>

// ---------------------------------------------------------------------------
// DummyTeModel: 6 chained NT GEMMs (dense w1,w2 then 2x grouped(g1,g2), G=4).
// GEMM: 256x256 tile, BK=64, 512 thr (8 waves, 2Mx4N), double-buffered LDS,
// 8-phase/2-K-tile schedule with counted vmcnt(8) (T3+T4), 3-bit XOR LDS
// swizzle via pre-swizzled global source (T2, rule #21), setprio (T5),
// bijective XCD block swizzle (T1). fp32->bf16 convert kernels unchanged.
// ---------------------------------------------------------------------------

typedef __bf16 bf16_t;
typedef __bf16 bf16x8 __attribute__((ext_vector_type(8)));
typedef float f32x4 __attribute__((ext_vector_type(4)));

#define BM 256
#define BN 256
#define BK 64

#define BARF() do { __builtin_amdgcn_s_barrier(); asm volatile("" ::: "memory"); } while (0)
#define LGKM0() do { asm volatile("s_waitcnt lgkmcnt(0)" ::: "memory"); \
                     __builtin_amdgcn_sched_barrier(0); } while (0)
#define VMCNT(n) asm volatile("s_waitcnt vmcnt(" #n ")" ::: "memory")

#define MFMA16(a, b, c) __builtin_amdgcn_mfma_f32_16x16x32_bf16(a, b, c, 0, 0, 0)

__device__ __forceinline__ void gload_lds16(const bf16_t* g, bf16_t* l) {
    __builtin_amdgcn_global_load_lds(
        (const __attribute__((address_space(1))) void*)g,
        (__attribute__((address_space(3))) void*)l, 16, 0, 0);
}

// C[g][m][n] = sum_k A[g][m][k] * B[g][n][k] + bias[g][n]
// Grid: (N/BN, M/BM, G). Block: 512 threads = 8 waves (2M x 4N), wave: 128x64.
template <typename OutT>
__global__ __launch_bounds__(512, 2) void gemm_bt_kernel(
    const bf16_t* __restrict__ A,    // [G, M, K]
    const bf16_t* __restrict__ B,    // [G, N, K]
    const float*  __restrict__ bias, // [G, N]
    OutT* __restrict__ C,            // [G, M, N]
    int M, int N, int K,
    long long sA, long long sB, long long sBias, long long sC)
{
    __shared__ __align__(16) bf16_t lds_a[2][BM * BK]; // 2 x 32 KB
    __shared__ __align__(16) bf16_t lds_b[2][BN * BK]; // 2 x 32 KB

    const int tid  = threadIdx.x;
    const int lane = tid & 63;
    const int wave = tid >> 6;
    const int wm   = wave >> 2;  // 0..1  (M half)
    const int wn   = wave & 3;   // 0..3  (N quarter)

    // T1: bijective XCD swizzle (all our grids have nwg % 8 == 0)
    const int gx = gridDim.x;
    int id = blockIdx.y * gx + blockIdx.x;
    const int chunk = (gx * gridDim.y) >> 3;
    id = (id & 7) * chunk + (id >> 3);
    const int bx = id % gx;
    const int by = id / gx;

    const int z = blockIdx.z;
    const bf16_t* Ab = A + z * sA + (long long)by * BM * K;
    const bf16_t* Bb = B + z * sB + (long long)bx * BN * K;
    const float* biasb = bias + z * sBias + (long long)bx * BN;

    // --- staging: 8 insts/thread/K-tile (4 A + 4 B), 16B each; linear LDS
    // dest (global_load_lds requirement), INVERSE-swizzled global source.
    // LDS layout: element (row, kbyte) lives at byte row*128 + (kbyte ^ ((row&7)<<4)).
    const bf16_t* pa[4];
    const bf16_t* pb[4];
    int ldoff[4];
#pragma unroll
    for (int j = 0; j < 4; ++j) {
        const int db  = j * 8192 + tid * 16;            // linear dest byte in tile
        const int row = db >> 7;                        // 0..255
        const int kb  = (db & 127) ^ ((row & 7) << 4);  // logical k-byte for this slot
        pa[j] = Ab + (long long)row * K + (kb >> 1);
        pb[j] = Bb + (long long)row * K + (kb >> 1);
        ldoff[j] = j * 4096 + wave * 512;               // element offset (wave-uniform)
    }

    // prologue: K-tile 0 -> buf0, K-tile 1 -> buf1; K0 landed, K1 in flight
#pragma unroll
    for (int j = 0; j < 4; ++j) {
        gload_lds16(pa[j], &lds_a[0][ldoff[j]]);
        gload_lds16(pb[j], &lds_b[0][ldoff[j]]);
    }
#pragma unroll
    for (int j = 0; j < 4; ++j) {
        gload_lds16(pa[j] + BK, &lds_a[1][ldoff[j]]);
        gload_lds16(pb[j] + BK, &lds_b[1][ldoff[j]]);
    }
    VMCNT(8);
    BARF();

    // LDS read addressing (applies the same XOR swizzle)
    const int l15  = lane & 15;
    const int ksw0 = ((lane >> 4) << 4) ^ ((lane & 7) << 4); // kstep 0 byte sel
    const int ksw1 = ksw0 ^ 64;                              // kstep 1
    const int abase = (wm * 128 + l15) * 128; // byte offset of lane's A row
    const int bbase = (wn * 64  + l15) * 128; // byte offset of lane's B row

    f32x4 acc[8][4] = {};
    const int nt = K / BK;

    for (int t = 0; t < nt; ++t) {
        const char* la = (const char*)lds_a[t & 1] + abase;
        const char* lb = (const char*)lds_b[t & 1] + bbase;
        bf16_t* sa = lds_a[t & 1];
        bf16_t* sb = lds_b[t & 1];
        const bool st = (t + 2) < nt;   // stage K-tile t+2 into buf t&1
        const int kk = (t + 2) * BK;

        bf16x8 af[8][2], bfr[4][2];

        // ---- phase 1: read a[0:4], b[0:2]; MFMA m0-3 x n0-1 ----
#pragma unroll
        for (int i = 0; i < 4; ++i) {
            af[i][0] = *(const bf16x8*)(la + i * 2048 + ksw0);
            af[i][1] = *(const bf16x8*)(la + i * 2048 + ksw1);
        }
#pragma unroll
        for (int j = 0; j < 2; ++j) {
            bfr[j][0] = *(const bf16x8*)(lb + j * 2048 + ksw0);
            bfr[j][1] = *(const bf16x8*)(lb + j * 2048 + ksw1);
        }
        BARF(); LGKM0();
        __builtin_amdgcn_s_setprio(1);
#pragma unroll
        for (int s = 0; s < 2; ++s)
#pragma unroll
            for (int i = 0; i < 4; ++i)
#pragma unroll
                for (int j = 0; j < 2; ++j)
                    acc[i][j] = MFMA16(af[i][s], bfr[j][s], acc[i][j]);
        __builtin_amdgcn_s_setprio(0);
        BARF();

        // ---- phase 2: read b[2:4]; MFMA m0-3 x n2-3 ----
#pragma unroll
        for (int j = 2; j < 4; ++j) {
            bfr[j][0] = *(const bf16x8*)(lb + j * 2048 + ksw0);
            bfr[j][1] = *(const bf16x8*)(lb + j * 2048 + ksw1);
        }
        BARF(); LGKM0();
        __builtin_amdgcn_s_setprio(1);
#pragma unroll
        for (int s = 0; s < 2; ++s)
#pragma unroll
            for (int i = 0; i < 4; ++i)
#pragma unroll
            for (int j = 2; j < 4; ++j)
                acc[i][j] = MFMA16(af[i][s], bfr[j][s], acc[i][j]);
        __builtin_amdgcn_s_setprio(0);
        BARF();

        // ---- phase 3: read a[4:8]; stage B(t+2) (B last read = ph2);
        //      MFMA m4-7 x n2-3 ----
#pragma unroll
        for (int i = 4; i < 8; ++i) {
            af[i][0] = *(const bf16x8*)(la + i * 2048 + ksw0);
            af[i][1] = *(const bf16x8*)(la + i * 2048 + ksw1);
        }
        if (st) {
#pragma unroll
            for (int j = 0; j < 4; ++j)
                gload_lds16(pb[j] + kk, &sb[ldoff[j]]);
        }
        BARF(); LGKM0();
        __builtin_amdgcn_s_setprio(1);
#pragma unroll
        for (int s = 0; s < 2; ++s)
#pragma unroll
            for (int i = 4; i < 8; ++i)
#pragma unroll
            for (int j = 2; j < 4; ++j)
                acc[i][j] = MFMA16(af[i][s], bfr[j][s], acc[i][j]);
        __builtin_amdgcn_s_setprio(0);
        BARF();

        // ---- phase 4: stage A(t+2) (A last read = ph3); counted fence;
        //      MFMA m4-7 x n0-1 ----
        if (st) {
#pragma unroll
            for (int j = 0; j < 4; ++j)
                gload_lds16(pa[j] + kk, &sa[ldoff[j]]);
            VMCNT(8);   // keep this tile's 8 stages in flight; older all landed
        } else {
            VMCNT(0);   // epilogue drain (last two K-tiles)
        }
        BARF();
        __builtin_amdgcn_s_setprio(1);
#pragma unroll
        for (int s = 0; s < 2; ++s)
#pragma unroll
            for (int i = 4; i < 8; ++i)
#pragma unroll
            for (int j = 0; j < 2; ++j)
                acc[i][j] = MFMA16(af[i][s], bfr[j][s], acc[i][j]);
        __builtin_amdgcn_s_setprio(0);
        BARF();
    }

    // Epilogue. C/D layout: col = lane&15, row = (lane>>4)*4 + reg  [m89/m91]
    const long long cz = z * sC;
    const int row_base = by * BM + wm * 128 + (lane >> 4) * 4;
    const int col_base = bx * BN + wn * 64 + l15;
#pragma unroll
    for (int j = 0; j < 4; ++j) {
        const float bb = biasb[wn * 64 + j * 16 + l15];
        const int col = col_base + j * 16;
#pragma unroll
        for (int i = 0; i < 8; ++i) {
            const int row0 = row_base + i * 16;
            OutT* Cp = C + cz + (long long)row0 * N + col;
#pragma unroll
            for (int r = 0; r < 4; ++r)
                Cp[(long long)r * N] = (OutT)(acc[i][j][r] + bb);
        }
    }
}

// fp32 -> bf16, 8 elements/thread (all sizes divisible by 2048)
__global__ __launch_bounds__(256) void f2bf_kernel(
    const float* __restrict__ in, bf16_t* __restrict__ out, int n8)
{
    int i = blockIdx.x * 256 + threadIdx.x;
    if (i >= n8) return;
    const float4* p = (const float4*)in + 2 * (long long)i;
    float4 a = p[0];
    float4 b = p[1];
    bf16x8 o;
    o[0] = (bf16_t)a.x; o[1] = (bf16_t)a.y; o[2] = (bf16_t)a.z; o[3] = (bf16_t)a.w;
    o[4] = (bf16_t)b.x; o[5] = (bf16_t)b.y; o[6] = (bf16_t)b.z; o[7] = (bf16_t)b.w;
    *((bf16x8*)out + i) = o;
}

static inline void f2bf(const float* in, bf16_t* out, long long n, hipStream_t s) {
    int n8 = (int)(n / 8);
    f2bf_kernel<<<dim3((n8 + 255) / 256), dim3(256), 0, s>>>(in, out, n8);
}

extern "C" void kernel_launch(void* const* d_in, const int* in_sizes, int n_in,
                              void* d_out, int out_size, void* d_ws, size_t ws_size,
                              hipStream_t stream) {
    // Problem constants
    const int H = 2048, I = 4096, T = 16384, G = 4;

    const float* x  = (const float*)d_in[0];  // [T, H]
    const float* w1 = (const float*)d_in[1];  // [2H, H]
    const float* b1 = (const float*)d_in[2];
    const float* w2 = (const float*)d_in[3];  // [H, 2H]
    const float* b2 = (const float*)d_in[4];
    const float* g1w[2] = {(const float*)d_in[5], (const float*)d_in[9]};
    const float* g1b[2] = {(const float*)d_in[6], (const float*)d_in[10]};
    const float* g2w[2] = {(const float*)d_in[7], (const float*)d_in[11]};
    const float* g2b[2] = {(const float*)d_in[8], (const float*)d_in[12]};
    float* out = (float*)d_out;

    // Workspace: XA (T x I bf16 = 134 MB) | XB (134 MB) | WB (67 MB)
    char* ws = (char*)d_ws;
    bf16_t* XA = (bf16_t*)ws;
    bf16_t* XB = (bf16_t*)(ws + 134217728LL);
    bf16_t* WB = (bf16_t*)(ws + 268435456LL);

    // x -> bf16
    f2bf(x, XA, (long long)T * H, stream);

    // dense 1: [T,H] @ [I,H]^T -> XB [T, I]
    f2bf(w1, WB, (long long)I * H, stream);
    gemm_bt_kernel<bf16_t><<<dim3(I / BN, T / BM, 1), dim3(512), 0, stream>>>(
        XA, WB, b1, XB, T, I, H, 0, 0, 0, 0);

    // dense 2: [T,I] @ [H,I]^T -> XA [T, H]
    f2bf(w2, WB, (long long)H * I, stream);
    gemm_bt_kernel<bf16_t><<<dim3(H / BN, T / BM, 1), dim3(512), 0, stream>>>(
        XB, WB, b2, XA, T, H, I, 0, 0, 0, 0);

    const long long Mg = T / G; // 4096 rows per group
    for (int li = 0; li < 2; ++li) {
        // g1: per group [4096,H] @ [I,H]^T -> XB
        f2bf(g1w[li], WB, (long long)G * I * H, stream);
        gemm_bt_kernel<bf16_t><<<dim3(I / BN, (int)(Mg / BM), G), dim3(512), 0, stream>>>(
            XA, WB, g1b[li], XB, (int)Mg, I, H,
            Mg * H, (long long)I * H, I, Mg * I);

        // g2: per group [4096,I] @ [H,I]^T -> XA (or d_out fp32 on last stage)
        f2bf(g2w[li], WB, (long long)G * H * I, stream);
        if (li == 0) {
            gemm_bt_kernel<bf16_t><<<dim3(H / BN, (int)(Mg / BM), G), dim3(512), 0, stream>>>(
                XB, WB, g2b[li], XA, (int)Mg, H, I,
                Mg * I, (long long)H * I, H, Mg * H);
        } else {
            gemm_bt_kernel<float><<<dim3(H / BN, (int)(Mg / BM), G), dim3(512), 0, stream>>>(
                XB, WB, g2b[li], out, (int)Mg, H, I,
                Mg * I, (long long)H * I, H, Mg * H);
        }
    }
}